// Round 5
// baseline (271.096 us; speedup 1.0000x reference)
//
#include <hip/hip_runtime.h>
#include <hip/hip_bf16.h>
#include <math.h>

#define B_ 2
#define L_ 2048
#define DM_ 512
#define H_ 8
#define DK_ 64
#define SCALE_ 0.125f   // 1/sqrt(64), folded into Q projection epilogue
#define KSPLIT 2

typedef __attribute__((ext_vector_type(8))) short short8;      // MFMA bf16 A/B frag
typedef __attribute__((ext_vector_type(8))) unsigned short ushort8;
typedef __attribute__((ext_vector_type(4))) float f32x4;       // MFMA C/D frag
typedef unsigned short u16;

__device__ __forceinline__ u16 f2bf(float x) {
    __hip_bfloat16 h = __float2bfloat16(x);
    u16 r; __builtin_memcpy(&r, &h, 2); return r;
}

// async global->LDS, 16B/lane; LDS dest is wave-uniform base + laneInWave*16
__device__ __forceinline__ void gld16(const u16* g, u16* l) {
    __builtin_amdgcn_global_load_lds(
        (const __attribute__((address_space(1))) void*)g,
        (__attribute__((address_space(3))) void*)l, 16, 0, 0);
}

// ---------------------------------------------------------------------------
// Fused fp32->bf16 conversion. Order: Wq,Wk,Wv,Wo (256K each), Q,K,V (2M each)
// -> contiguous bf16 at dst. 8 elems/thread, 3584 blocks.
// ---------------------------------------------------------------------------
__global__ __launch_bounds__(256)
void cvt7(const float* __restrict__ s0, const float* __restrict__ s1,
          const float* __restrict__ s2, const float* __restrict__ s3,
          const float* __restrict__ s4, const float* __restrict__ s5,
          const float* __restrict__ s6, u16* __restrict__ dst)
{
    const size_t NW = 262144, NB = 2097152;
    size_t i = ((size_t)blockIdx.x * 256 + threadIdx.x) * 8;
    const float* s; size_t off;
    if      (i < NW)            { s = s0; off = 0; }
    else if (i < 2*NW)          { s = s1; off = NW; }
    else if (i < 3*NW)          { s = s2; off = 2*NW; }
    else if (i < 4*NW)          { s = s3; off = 3*NW; }
    else if (i < 4*NW + NB)     { s = s4; off = 4*NW; }
    else if (i < 4*NW + 2*NB)   { s = s5; off = 4*NW + NB; }
    else                        { s = s6; off = 4*NW + 2*NB; }
    const float* p = s + (i - off);
    float4 x = *(const float4*)p;
    float4 y = *(const float4*)(p + 4);
    ushort8 o;
    o[0]=f2bf(x.x); o[1]=f2bf(x.y); o[2]=f2bf(x.z); o[3]=f2bf(x.w);
    o[4]=f2bf(y.x); o[5]=f2bf(y.y); o[6]=f2bf(y.z); o[7]=f2bf(y.w);
    *(ushort8*)&dst[i] = o;
}

// ---------------------------------------------------------------------------
// Fused Q/K/V projection GEMM (blockIdx.z selects). 64x64 tile, BK=64,
// 2-phase double-buffered LDS (stage next -> compute cur -> one barrier).
// z=0: qw [B,H,L,DK] bf16, *SCALE_.  z=1: kw same, *1.  z=2: vtw [B,H,DK,L].
// ---------------------------------------------------------------------------
__global__ __launch_bounds__(256)
void proj3(const u16* __restrict__ Xq, const u16* __restrict__ Xk,
           const u16* __restrict__ Xv, const u16* __restrict__ Wqb,
           const u16* __restrict__ Wkb, const u16* __restrict__ Wvb,
           const float* __restrict__ bq, const float* __restrict__ bk,
           const float* __restrict__ bv, u16* __restrict__ qw,
           u16* __restrict__ kw, u16* __restrict__ vtw)
{
    __shared__ u16 Xs[2][64*64];
    __shared__ u16 Ws[2][64*64];

    const int z = blockIdx.z;
    const u16* X = (z==0) ? Xq : (z==1) ? Xk : Xv;
    const u16* W = (z==0) ? Wqb : (z==1) ? Wkb : Wvb;
    const float* bias = (z==0) ? bq : (z==1) ? bk : bv;

    const int t = threadIdx.x;
    const int w = t >> 6, lw = t & 63;
    const int g = lw >> 4, c15 = lw & 15;
    const int m0 = blockIdx.x * 64, n0 = blockIdx.y * 64;
    const int rs0 = w*8 + (lw >> 3);
    const int cs0 = lw & 7;
    const int arow = w*16 + c15;

    f32x4 acc[4];
    #pragma unroll
    for (int nt = 0; nt < 4; ++nt) acc[nt] = f32x4{0.f,0.f,0.f,0.f};

    // prologue stage k0=0 into buf 0
    #pragma unroll
    for (int j = 0; j < 2; ++j) {
        const int r = rs0 + j*32;
        const int csrc = (cs0 ^ (r & 7)) * 8;
        gld16(X + (size_t)(m0 + r)*DM_ + csrc, &Xs[0][w*512 + j*2048]);
        gld16(W + (size_t)(n0 + r)*DM_ + csrc, &Ws[0][w*512 + j*2048]);
    }
    __syncthreads();

    int buf = 0;
    for (int k0 = 0; k0 < DM_; k0 += 64) {
        if (k0 + 64 < DM_) {
            #pragma unroll
            for (int j = 0; j < 2; ++j) {
                const int r = rs0 + j*32;
                const int csrc = (cs0 ^ (r & 7)) * 8;
                gld16(X + (size_t)(m0 + r)*DM_ + k0 + 64 + csrc, &Xs[buf^1][w*512 + j*2048]);
                gld16(W + (size_t)(n0 + r)*DM_ + k0 + 64 + csrc, &Ws[buf^1][w*512 + j*2048]);
            }
        }
        #pragma unroll
        for (int ks = 0; ks < 2; ++ks) {
            short8 a = *(const short8*)&Xs[buf][arow*64 + (((ks*4 + g) ^ (arow & 7)) * 8)];
            #pragma unroll
            for (int nt = 0; nt < 4; ++nt) {
                const int brow = nt*16 + c15;
                short8 b = *(const short8*)&Ws[buf][brow*64 + (((ks*4 + g) ^ (brow & 7)) * 8)];
                acc[nt] = __builtin_amdgcn_mfma_f32_16x16x32_bf16(a, b, acc[nt], 0, 0, 0);
            }
        }
        __syncthreads();   // drains vmcnt -> next buf ready; cur buf free to overwrite
        buf ^= 1;
    }

    // C/D: row = 4*(lane>>4)+reg, col = lane&15
    const int h  = blockIdx.y;        // n0>>6
    const int bb = m0 >> 11;
    const int l0 = m0 & (L_ - 1);
    if (z < 2) {
        u16* out = (z == 0) ? qw : kw;
        const float sc = (z == 0) ? SCALE_ : 1.0f;
        #pragma unroll
        for (int nt = 0; nt < 4; ++nt) {
            const int dk = nt*16 + c15;
            const float bv2 = bias[n0 + dk];
            #pragma unroll
            for (int reg = 0; reg < 4; ++reg) {
                const int l = l0 + w*16 + 4*g + reg;
                out[(((size_t)bb*H_ + h)*L_ + l)*DK_ + dk] =
                    f2bf((acc[nt][reg] + bv2) * sc);
            }
        }
    } else {
        #pragma unroll
        for (int nt = 0; nt < 4; ++nt) {
            const int dk = nt*16 + c15;
            const float bv2 = bias[n0 + dk];
            ushort4 o4;
            o4.x = f2bf(acc[nt][0] + bv2);
            o4.y = f2bf(acc[nt][1] + bv2);
            o4.z = f2bf(acc[nt][2] + bv2);
            o4.w = f2bf(acc[nt][3] + bv2);
            const int l = l0 + w*16 + 4*g;     // 4 consecutive l (reg) -> 8B store
            *(ushort4*)&vtw[(((size_t)bb*H_ + h)*DK_ + dk)*L_ + l] = o4;
        }
    }
}

// ---------------------------------------------------------------------------
// Flash attention, bf16 MFMA, fp32 accum, BARRIER-FREE.
// K/V fragments read directly from global (L2-resident: 256KB/head each).
// Grid (bh=16, qt=32, ks=KSPLIT): bh fastest -> same-head blocks cluster per
// XCD. Each block: 4 independent waves x 16 q-rows over L/KSPLIT keys.
// Outputs UNNORMALIZED f32 partials Op[ks][bh][l][dk] + ml[ks][bh][l]=(m,l).
// ---------------------------------------------------------------------------
__global__ __launch_bounds__(256)
void attn_split(const u16* __restrict__ qg, const u16* __restrict__ kg,
                const u16* __restrict__ vtg, float* __restrict__ Op,
                float2* __restrict__ ml)
{
    __shared__ float Ps[4][16*68];   // per-wave P buffer (C-layout -> A-frag)

    const int t = threadIdx.x;
    const int w = t >> 6, lw = t & 63;
    const int g = lw >> 4, c15 = lw & 15;
    const int bh = blockIdx.x, qt = blockIdx.y, ks = blockIdx.z;

    const u16* qp = qg + ((size_t)bh*L_ + qt*64 + w*16) * DK_;
    const u16* kp = kg + (size_t)bh*L_*DK_;
    const u16* vp = vtg + (size_t)bh*DK_*L_;

    // Q A-frag: row = lane&15, k = (lane>>4)*8 + elem (pre-scaled at proj)
    short8 qf0 = *(const short8*)&qp[c15*DK_ + g*8];
    short8 qf1 = *(const short8*)&qp[c15*DK_ + 32 + g*8];

    f32x4 o[4];
    #pragma unroll
    for (int dt = 0; dt < 4; ++dt) o[dt] = f32x4{0.f,0.f,0.f,0.f};
    float m_run[4] = {-1e30f,-1e30f,-1e30f,-1e30f};
    float l_run[4] = {0.f,0.f,0.f,0.f};
    float* Pw = &Ps[w][0];

    const int nt_tiles = L_ / 64 / KSPLIT;
    for (int kt = ks*nt_tiles; kt < (ks+1)*nt_tiles; ++kt) {
        const u16* kbase = kp + (size_t)kt*64*DK_;

        // S = Q K^T : B-frag (col=lane&15=key, k=(lane>>4)*8+e) direct global
        f32x4 s[4];
        #pragma unroll
        for (int nt = 0; nt < 4; ++nt) s[nt] = f32x4{0.f,0.f,0.f,0.f};
        #pragma unroll
        for (int ku = 0; ku < 2; ++ku) {
            short8 aq = ku ? qf1 : qf0;
            #pragma unroll
            for (int nt = 0; nt < 4; ++nt) {
                short8 b = *(const short8*)&kbase[(size_t)(nt*16 + c15)*DK_ + ku*32 + g*8];
                s[nt] = __builtin_amdgcn_mfma_f32_16x16x32_bf16(aq, b, s[nt], 0, 0, 0);
            }
        }

        // online softmax; row q=4g+reg lives across the 16 lanes of (lane>>4)
        float mx[4], fr[4], psum[4];
        #pragma unroll
        for (int reg = 0; reg < 4; ++reg)
            mx[reg] = fmaxf(fmaxf(s[0][reg], s[1][reg]), fmaxf(s[2][reg], s[3][reg]));
        #pragma unroll
        for (int off = 1; off < 16; off <<= 1) {
            #pragma unroll
            for (int reg = 0; reg < 4; ++reg)
                mx[reg] = fmaxf(mx[reg], __shfl_xor(mx[reg], off, 64));
        }
        #pragma unroll
        for (int reg = 0; reg < 4; ++reg) {
            const float mn = fmaxf(m_run[reg], mx[reg]);
            fr[reg] = __expf(m_run[reg] - mn);
            m_run[reg] = mn;
            psum[reg] = 0.f;
        }
        #pragma unroll
        for (int nt = 0; nt < 4; ++nt) {
            #pragma unroll
            for (int reg = 0; reg < 4; ++reg) {
                const float p = __expf(s[nt][reg] - m_run[reg]);
                Pw[(4*g + reg)*68 + nt*16 + c15] = p;
                psum[reg] += p;
            }
        }
        #pragma unroll
        for (int off = 1; off < 16; off <<= 1) {
            #pragma unroll
            for (int reg = 0; reg < 4; ++reg)
                psum[reg] += __shfl_xor(psum[reg], off, 64);
        }
        f32x4 fv; fv[0]=fr[0]; fv[1]=fr[1]; fv[2]=fr[2]; fv[3]=fr[3];
        #pragma unroll
        for (int reg = 0; reg < 4; ++reg)
            l_run[reg] = l_run[reg]*fr[reg] + psum[reg];
        #pragma unroll
        for (int dt = 0; dt < 4; ++dt) o[dt] *= fv;

        // PV: P A-frag via per-wave LDS (same-wave, lgkmcnt-ordered);
        // V^T B-frag (col=lane&15=d, k=key) direct global
        #pragma unroll
        for (int ku = 0; ku < 2; ++ku) {
            const float* pr = &Pw[c15*68 + ku*32 + g*8];
            float4 plo = *(const float4*)pr;
            float4 phi = *(const float4*)(pr + 4);
            short8 pa;
            pa[0]=(short)f2bf(plo.x); pa[1]=(short)f2bf(plo.y);
            pa[2]=(short)f2bf(plo.z); pa[3]=(short)f2bf(plo.w);
            pa[4]=(short)f2bf(phi.x); pa[5]=(short)f2bf(phi.y);
            pa[6]=(short)f2bf(phi.z); pa[7]=(short)f2bf(phi.w);
            #pragma unroll
            for (int dt = 0; dt < 4; ++dt) {
                short8 vb = *(const short8*)&vp[(size_t)(dt*16 + c15)*L_ + kt*64 + ku*32 + g*8];
                o[dt] = __builtin_amdgcn_mfma_f32_16x16x32_bf16(pa, vb, o[dt], 0, 0, 0);
            }
        }
    }

    // store unnormalized partials + (m,l)
    const int qbase = qt*64 + w*16;
    #pragma unroll
    for (int reg = 0; reg < 4; ++reg) {
        if (c15 == 0) {
            const int qrow = qbase + 4*g + reg;
            ml[((size_t)ks*16 + bh)*L_ + qrow] = float2{m_run[reg], l_run[reg]};
        }
    }
    float* op = Op + ((size_t)ks*16 + bh)*L_*DK_;
    #pragma unroll
    for (int dt = 0; dt < 4; ++dt)
        #pragma unroll
        for (int reg = 0; reg < 4; ++reg)
            op[(size_t)(qbase + 4*g + reg)*DK_ + dt*16 + c15] = o[dt][reg];
}

// ---------------------------------------------------------------------------
// Combine KSPLIT partials -> bf16 context cw [B, L, H*DK].
// 16 rows x 16 d-quads per 256-thread block; 2048 blocks.
// ---------------------------------------------------------------------------
__global__ __launch_bounds__(256)
void combine(const float* __restrict__ Op, const float2* __restrict__ ml,
             u16* __restrict__ cw)
{
    const int t = threadIdx.x;
    const size_t row = (size_t)blockIdx.x*16 + (t >> 4);  // 0..32767 (= bh*L + l)
    const int di = (t & 15) * 4;
    const float2 a = ml[row];
    const float2 b = ml[32768 + row];
    const float M  = fmaxf(a.x, b.x);
    const float e0 = __expf(a.x - M), e1 = __expf(b.x - M);
    const float inv = 1.0f / (a.y*e0 + b.y*e1);
    float4 x = *(const float4*)&Op[row*DK_ + di];
    float4 y = *(const float4*)&Op[(32768 + row)*DK_ + di];
    const int bh = (int)(row >> 11), l = (int)(row & 2047);
    const int bb = bh >> 3, h = bh & 7;
    ushort4 o4;
    o4.x = f2bf((x.x*e0 + y.x*e1) * inv);
    o4.y = f2bf((x.y*e0 + y.y*e1) * inv);
    o4.z = f2bf((x.z*e0 + y.z*e1) * inv);
    o4.w = f2bf((x.w*e0 + y.w*e1) * inv);
    *(ushort4*)&cw[((size_t)bb*L_ + l)*DM_ + h*DK_ + di] = o4;
}

// ---------------------------------------------------------------------------
// Final projection: out = cw @ Wo^T + bo, fp32 out. Same 2-phase structure.
// ---------------------------------------------------------------------------
__global__ __launch_bounds__(256)
void gemmO(const u16* __restrict__ X, const u16* __restrict__ W,
           const float* __restrict__ bias, float* __restrict__ out)
{
    __shared__ u16 Xs[2][64*64];
    __shared__ u16 Ws[2][64*64];

    const int t = threadIdx.x;
    const int w = t >> 6, lw = t & 63;
    const int g = lw >> 4, c15 = lw & 15;
    const int m0 = blockIdx.x * 64, n0 = blockIdx.y * 64;
    const int rs0 = w*8 + (lw >> 3);
    const int cs0 = lw & 7;
    const int arow = w*16 + c15;

    f32x4 acc[4];
    #pragma unroll
    for (int nt = 0; nt < 4; ++nt) acc[nt] = f32x4{0.f,0.f,0.f,0.f};

    #pragma unroll
    for (int j = 0; j < 2; ++j) {
        const int r = rs0 + j*32;
        const int csrc = (cs0 ^ (r & 7)) * 8;
        gld16(X + (size_t)(m0 + r)*DM_ + csrc, &Xs[0][w*512 + j*2048]);
        gld16(W + (size_t)(n0 + r)*DM_ + csrc, &Ws[0][w*512 + j*2048]);
    }
    __syncthreads();

    int buf = 0;
    for (int k0 = 0; k0 < DM_; k0 += 64) {
        if (k0 + 64 < DM_) {
            #pragma unroll
            for (int j = 0; j < 2; ++j) {
                const int r = rs0 + j*32;
                const int csrc = (cs0 ^ (r & 7)) * 8;
                gld16(X + (size_t)(m0 + r)*DM_ + k0 + 64 + csrc, &Xs[buf^1][w*512 + j*2048]);
                gld16(W + (size_t)(n0 + r)*DM_ + k0 + 64 + csrc, &Ws[buf^1][w*512 + j*2048]);
            }
        }
        #pragma unroll
        for (int ks = 0; ks < 2; ++ks) {
            short8 a = *(const short8*)&Xs[buf][arow*64 + (((ks*4 + g) ^ (arow & 7)) * 8)];
            #pragma unroll
            for (int nt = 0; nt < 4; ++nt) {
                const int brow = nt*16 + c15;
                short8 b = *(const short8*)&Ws[buf][brow*64 + (((ks*4 + g) ^ (brow & 7)) * 8)];
                acc[nt] = __builtin_amdgcn_mfma_f32_16x16x32_bf16(a, b, acc[nt], 0, 0, 0);
            }
        }
        __syncthreads();
        buf ^= 1;
    }

    #pragma unroll
    for (int nt = 0; nt < 4; ++nt) {
        const int n = n0 + nt*16 + c15;
        const float bv = bias[n];
        #pragma unroll
        for (int reg = 0; reg < 4; ++reg) {
            const int m = m0 + w*16 + 4*g + reg;
            out[(size_t)m * DM_ + n] = acc[nt][reg] + bv;
        }
    }
}

// ---------------------------------------------------------------------------
extern "C" void kernel_launch(void* const* d_in, const int* in_sizes, int n_in,
                              void* d_out, int out_size, void* d_ws, size_t ws_size,
                              hipStream_t stream)
{
    const float* Q  = (const float*)d_in[0];
    const float* K  = (const float*)d_in[1];
    const float* V  = (const float*)d_in[2];
    const float* Wq = (const float*)d_in[3];
    const float* bq = (const float*)d_in[4];
    const float* Wk = (const float*)d_in[5];
    const float* bk = (const float*)d_in[6];
    const float* Wv = (const float*)d_in[7];
    const float* bv = (const float*)d_in[8];
    const float* Wo = (const float*)d_in[9];
    const float* bo = (const float*)d_in[10];
    // d_in[11] = index_sample: provably unused (n_top == L -> top_k is a
    // permutation -> the scatter overwrites the whole mean-context baseline).

    char* w8 = (char*)d_ws;
    const size_t MB = 1u << 20;
    // bf16 conversions at offset 0: Wq,Wk,Wv,Wo (0..2MB), Q,K,V (2..14MB)
    u16* Wqb = (u16*)(w8);
    u16* Wkb = Wqb + 262144;
    u16* Wvb = Wkb + 262144;
    u16* Wob = Wvb + 262144;
    u16* Qb  = Wob + 262144;          // byte offset 2MB
    u16* Kb  = Qb + 2097152;
    u16* Vb  = Kb + 2097152;
    // Op partials (2 x 8MB f32) ALIAS Qb..Vb (dead after proj3): bytes 2..18MB
    float*  Op = (float*)(w8 + 2*MB);
    float2* ml = (float2*)(w8 + 18*MB);          // 512KB
    u16* qw  = (u16*)(w8 + 19*MB);               // [B,H,L,DK] bf16, pre-scaled
    u16* kw  = (u16*)(w8 + 23*MB);               // [B,H,L,DK] bf16
    u16* vtw = (u16*)(w8 + 27*MB);               // [B,H,DK,L] bf16
    u16* cw  = (u16*)(w8 + 19*MB);               // ALIAS qw/kw (dead after attn)

    cvt7<<<3584, 256, 0, stream>>>(Wq, Wk, Wv, Wo, Q, K, V, Wqb);

    dim3 blk(256);
    proj3<<<dim3(64, 8, 3), blk, 0, stream>>>(Qb, Kb, Vb, Wqb, Wkb, Wvb,
                                              bq, bk, bv, qw, kw, vtw);

    attn_split<<<dim3(16, 32, KSPLIT), blk, 0, stream>>>(qw, kw, vtw, Op, ml);

    combine<<<2048, blk, 0, stream>>>(Op, ml, cw);

    gemmO<<<dim3(64, 8), blk, 0, stream>>>(cw, Wob, bo, (float*)d_out);
}

// Round 6
// 178.389 us; speedup vs baseline: 1.5197x; 1.5197x over previous
//
#include <hip/hip_runtime.h>
#include <hip/hip_bf16.h>
#include <math.h>

#define B_ 2
#define L_ 2048
#define DM_ 512
#define H_ 8
#define DK_ 64
#define SCALE_ 0.125f   // 1/sqrt(64), folded into Q projection epilogue
#define KSPLIT 2
#define KTILES (L_ / 64 / KSPLIT)   // 16 key-tiles per split

typedef __attribute__((ext_vector_type(8))) short short8;      // MFMA bf16 A/B frag
typedef __attribute__((ext_vector_type(8))) unsigned short ushort8;
typedef __attribute__((ext_vector_type(4))) float f32x4;       // MFMA C/D frag
typedef unsigned short u16;

__device__ __forceinline__ u16 f2bf(float x) {
    __hip_bfloat16 h = __float2bfloat16(x);
    u16 r; __builtin_memcpy(&r, &h, 2); return r;
}

// async global->LDS, 16B/lane; LDS dest is wave-uniform base + laneInWave*16
__device__ __forceinline__ void gld16(const u16* g, u16* l) {
    __builtin_amdgcn_global_load_lds(
        (const __attribute__((address_space(1))) void*)g,
        (__attribute__((address_space(3))) void*)l, 16, 0, 0);
}

// ---------------------------------------------------------------------------
// Fused fp32->bf16 conversion. Order: Wq,Wk,Wv,Wo (256K each), Q,K,V (2M each)
// -> contiguous bf16 at dst. 8 elems/thread, 3584 blocks.
// ---------------------------------------------------------------------------
__global__ __launch_bounds__(256)
void cvt7(const float* __restrict__ s0, const float* __restrict__ s1,
          const float* __restrict__ s2, const float* __restrict__ s3,
          const float* __restrict__ s4, const float* __restrict__ s5,
          const float* __restrict__ s6, u16* __restrict__ dst)
{
    const size_t NW = 262144, NB = 2097152;
    size_t i = ((size_t)blockIdx.x * 256 + threadIdx.x) * 8;
    const float* s; size_t off;
    if      (i < NW)            { s = s0; off = 0; }
    else if (i < 2*NW)          { s = s1; off = NW; }
    else if (i < 3*NW)          { s = s2; off = 2*NW; }
    else if (i < 4*NW)          { s = s3; off = 3*NW; }
    else if (i < 4*NW + NB)     { s = s4; off = 4*NW; }
    else if (i < 4*NW + 2*NB)   { s = s5; off = 4*NW + NB; }
    else                        { s = s6; off = 4*NW + 2*NB; }
    const float* p = s + (i - off);
    float4 x = *(const float4*)p;
    float4 y = *(const float4*)(p + 4);
    ushort8 o;
    o[0]=f2bf(x.x); o[1]=f2bf(x.y); o[2]=f2bf(x.z); o[3]=f2bf(x.w);
    o[4]=f2bf(y.x); o[5]=f2bf(y.y); o[6]=f2bf(y.z); o[7]=f2bf(y.w);
    *(ushort8*)&dst[i] = o;
}

// ---------------------------------------------------------------------------
// Fused Q/K/V projection GEMM, 128x128 tile, BK=64, 4 waves (2x2, 64x64 each),
// 2-phase double-buffered LDS. blockIdx.z selects Q/K/V.
// z=0: qw [B,H,L,DK] bf16 *SCALE_.  z=1: kw same *1.  z=2: vtw [B,H,DK,L].
// ---------------------------------------------------------------------------
__global__ __launch_bounds__(256)
void proj3(const u16* __restrict__ Xq, const u16* __restrict__ Xk,
           const u16* __restrict__ Xv, const u16* __restrict__ Wqb,
           const u16* __restrict__ Wkb, const u16* __restrict__ Wvb,
           const float* __restrict__ bq, const float* __restrict__ bk,
           const float* __restrict__ bv, u16* __restrict__ qw,
           u16* __restrict__ kw, u16* __restrict__ vtw)
{
    __shared__ u16 As[2][128*64];   // 32 KB
    __shared__ u16 Bs[2][128*64];   // 32 KB  (total 64 KB -> 2 blocks/CU)

    const int z = blockIdx.z;
    const u16* X = (z==0) ? Xq : (z==1) ? Xk : Xv;
    const u16* W = (z==0) ? Wqb : (z==1) ? Wkb : Wvb;
    const float* bias = (z==0) ? bq : (z==1) ? bk : bv;

    const int t = threadIdx.x;
    const int w = t >> 6, lw = t & 63;
    const int g = lw >> 4, c15 = lw & 15;
    const int wx = w & 1, wy = w >> 1;        // wave tile: rows wy*64, cols wx*64
    const int m0 = blockIdx.x * 128, n0 = blockIdx.y * 128;
    const int rs0 = w*8 + (lw >> 3);
    const int cs0 = lw & 7;

    f32x4 acc[4][4];
    #pragma unroll
    for (int mi = 0; mi < 4; ++mi)
        #pragma unroll
        for (int ni = 0; ni < 4; ++ni) acc[mi][ni] = f32x4{0.f,0.f,0.f,0.f};

    // prologue: stage k0=0 into buf 0 (128 rows each of X,W; 4 gld16/wave each)
    #pragma unroll
    for (int j = 0; j < 4; ++j) {
        const int r = rs0 + j*32;
        const int csrc = (cs0 ^ (r & 7)) * 8;
        gld16(X + (size_t)(m0 + r)*DM_ + csrc, &As[0][w*512 + j*2048]);
        gld16(W + (size_t)(n0 + r)*DM_ + csrc, &Bs[0][w*512 + j*2048]);
    }
    __syncthreads();

    int buf = 0;
    for (int k0 = 0; k0 < DM_; k0 += 64) {
        if (k0 + 64 < DM_) {
            #pragma unroll
            for (int j = 0; j < 4; ++j) {
                const int r = rs0 + j*32;
                const int csrc = (cs0 ^ (r & 7)) * 8;
                gld16(X + (size_t)(m0 + r)*DM_ + k0 + 64 + csrc, &As[buf^1][w*512 + j*2048]);
                gld16(W + (size_t)(n0 + r)*DM_ + k0 + 64 + csrc, &Bs[buf^1][w*512 + j*2048]);
            }
        }
        #pragma unroll
        for (int ks = 0; ks < 2; ++ks) {
            short8 af[4], bf[4];
            #pragma unroll
            for (int mi = 0; mi < 4; ++mi) {
                const int ar = wy*64 + mi*16 + c15;
                af[mi] = *(const short8*)&As[buf][ar*64 + (((ks*4 + g) ^ (ar & 7)) * 8)];
            }
            #pragma unroll
            for (int ni = 0; ni < 4; ++ni) {
                const int br = wx*64 + ni*16 + c15;
                bf[ni] = *(const short8*)&Bs[buf][br*64 + (((ks*4 + g) ^ (br & 7)) * 8)];
            }
            #pragma unroll
            for (int mi = 0; mi < 4; ++mi)
                #pragma unroll
                for (int ni = 0; ni < 4; ++ni)
                    acc[mi][ni] = __builtin_amdgcn_mfma_f32_16x16x32_bf16(
                        af[mi], bf[ni], acc[mi][ni], 0, 0, 0);
        }
        __syncthreads();
        buf ^= 1;
    }

    // C/D: row = 4*(lane>>4)+reg, col = lane&15
    const int bb = m0 >> 11;
    const int l0 = m0 & (L_ - 1);
    if (z < 2) {
        u16* out = (z == 0) ? qw : kw;
        const float sc = (z == 0) ? SCALE_ : 1.0f;
        #pragma unroll
        for (int ni = 0; ni < 4; ++ni) {
            const int n = n0 + wx*64 + ni*16 + c15;
            const int h = n >> 6, dk = n & 63;
            const float bv2 = bias[n];
            #pragma unroll
            for (int mi = 0; mi < 4; ++mi) {
                #pragma unroll
                for (int reg = 0; reg < 4; ++reg) {
                    const int l = l0 + wy*64 + mi*16 + 4*g + reg;
                    out[(((size_t)bb*H_ + h)*L_ + l)*DK_ + dk] =
                        f2bf((acc[mi][ni][reg] + bv2) * sc);
                }
            }
        }
    } else {
        #pragma unroll
        for (int ni = 0; ni < 4; ++ni) {
            const int n = n0 + wx*64 + ni*16 + c15;
            const int h = n >> 6, dk = n & 63;
            const float bv2 = bias[n];
            #pragma unroll
            for (int mi = 0; mi < 4; ++mi) {
                const int l = l0 + wy*64 + mi*16 + 4*g;   // 4 consecutive l (reg)
                ushort4 o4;
                o4.x = f2bf(acc[mi][ni][0] + bv2);
                o4.y = f2bf(acc[mi][ni][1] + bv2);
                o4.z = f2bf(acc[mi][ni][2] + bv2);
                o4.w = f2bf(acc[mi][ni][3] + bv2);
                *(ushort4*)&vtw[(((size_t)bb*H_ + h)*DK_ + dk)*L_ + l] = o4;
            }
        }
    }
}

// ---------------------------------------------------------------------------
// Flash attention, bf16 MFMA, fp32 accum. K/V staged to LDS, double-buffered
// (T3-minimum 2-phase: stage t+1 -> compute t -> ONE barrier). KSPLIT=2.
// Grid (bh=16, qt=32, ks=2) = 1024 blocks; 4 waves x 16 q-rows.
// P routed through per-wave bf16 LDS with 16B-chunk XOR swizzle.
// LDS total = 2*8K (K) + 2*8K (V) + 4*2K (P) = 40 KB -> 4 blocks/CU.
// Outputs UNNORMALIZED f32 partials Op[ks][bh][l][dk] + ml[ks][bh][l]=(m,l).
// ---------------------------------------------------------------------------
__global__ __launch_bounds__(256)
void attn_kv(const u16* __restrict__ qg, const u16* __restrict__ kg,
             const u16* __restrict__ vtg, float* __restrict__ Op,
             float2* __restrict__ ml)
{
    __shared__ u16 Ks[2][64*64];
    __shared__ u16 Vs[2][64*64];
    __shared__ u16 Ps[4][16*64];   // per-wave P (bf16), XOR-swizzled 16B chunks

    const int t = threadIdx.x;
    const int w = t >> 6, lw = t & 63;
    const int g = lw >> 4, c15 = lw & 15;
    const int bh = blockIdx.x, qt = blockIdx.y, ksp = blockIdx.z;

    const u16* qp = qg + ((size_t)bh*L_ + qt*64 + w*16) * DK_;
    const u16* kp = kg + (size_t)bh*L_*DK_;
    const u16* vp = vtg + (size_t)bh*DK_*L_;

    // Q A-frag: row = lane&15, k = (lane>>4)*8 + elem (pre-scaled at proj)
    short8 qf0 = *(const short8*)&qp[c15*DK_ + g*8];
    short8 qf1 = *(const short8*)&qp[c15*DK_ + 32 + g*8];

    f32x4 o[4];
    #pragma unroll
    for (int dt = 0; dt < 4; ++dt) o[dt] = f32x4{0.f,0.f,0.f,0.f};
    float m_run[4] = {-1e30f,-1e30f,-1e30f,-1e30f};
    float l_run[4] = {0.f,0.f,0.f,0.f};
    u16* Pw = &Ps[w][0];

    const int rs0 = w*8 + (lw >> 3);
    const int cs0 = lw & 7;

    // prologue: stage first tile into buf 0
    {
        const int kt = ksp * KTILES;
        #pragma unroll
        for (int j = 0; j < 2; ++j) {
            const int r = rs0 + j*32;
            const int csrc = (cs0 ^ (r & 7)) * 8;
            gld16(kp + (size_t)(kt*64 + r)*DK_ + csrc, &Ks[0][w*512 + j*2048]);
            gld16(vp + (size_t)r*L_ + kt*64 + csrc,    &Vs[0][w*512 + j*2048]);
        }
    }
    __syncthreads();

    int buf = 0;
    for (int tt = 0; tt < KTILES; ++tt) {
        const int kt = ksp * KTILES + tt;

        // stage next tile into buf^1 (lands under this tile's compute)
        if (tt + 1 < KTILES) {
            #pragma unroll
            for (int j = 0; j < 2; ++j) {
                const int r = rs0 + j*32;
                const int csrc = (cs0 ^ (r & 7)) * 8;
                gld16(kp + (size_t)((kt+1)*64 + r)*DK_ + csrc, &Ks[buf^1][w*512 + j*2048]);
                gld16(vp + (size_t)r*L_ + (kt+1)*64 + csrc,    &Vs[buf^1][w*512 + j*2048]);
            }
        }

        // S = Q K^T  (16 q-rows x 64 keys per wave)
        f32x4 s[4];
        #pragma unroll
        for (int nt = 0; nt < 4; ++nt) s[nt] = f32x4{0.f,0.f,0.f,0.f};
        #pragma unroll
        for (int ku = 0; ku < 2; ++ku) {
            short8 aq = ku ? qf1 : qf0;
            #pragma unroll
            for (int nt = 0; nt < 4; ++nt) {
                const int key = nt*16 + c15;
                short8 b = *(const short8*)&Ks[buf][key*64 + (((ku*4 + g) ^ (key & 7)) * 8)];
                s[nt] = __builtin_amdgcn_mfma_f32_16x16x32_bf16(aq, b, s[nt], 0, 0, 0);
            }
        }

        // online softmax; row q=4g+reg lives across the 16 lanes of (lane>>4)
        float mx[4], fr[4], psum[4];
        #pragma unroll
        for (int reg = 0; reg < 4; ++reg)
            mx[reg] = fmaxf(fmaxf(s[0][reg], s[1][reg]), fmaxf(s[2][reg], s[3][reg]));
        #pragma unroll
        for (int off = 1; off < 16; off <<= 1) {
            #pragma unroll
            for (int reg = 0; reg < 4; ++reg)
                mx[reg] = fmaxf(mx[reg], __shfl_xor(mx[reg], off, 64));
        }
        #pragma unroll
        for (int reg = 0; reg < 4; ++reg) {
            const float mn = fmaxf(m_run[reg], mx[reg]);
            fr[reg] = __expf(m_run[reg] - mn);
            m_run[reg] = mn;
            psum[reg] = 0.f;
        }
        // P -> bf16 LDS (C-layout position, 16B-chunk XOR swizzle on row&7)
        #pragma unroll
        for (int nt = 0; nt < 4; ++nt) {
            #pragma unroll
            for (int reg = 0; reg < 4; ++reg) {
                const float p = __expf(s[nt][reg] - m_run[reg]);
                const int r = 4*g + reg;
                Pw[r*64 + ((nt*16 + c15) ^ ((r & 7) << 3))] = f2bf(p);
                psum[reg] += p;
            }
        }
        #pragma unroll
        for (int off = 1; off < 16; off <<= 1) {
            #pragma unroll
            for (int reg = 0; reg < 4; ++reg)
                psum[reg] += __shfl_xor(psum[reg], off, 64);
        }
        f32x4 fv; fv[0]=fr[0]; fv[1]=fr[1]; fv[2]=fr[2]; fv[3]=fr[3];
        #pragma unroll
        for (int reg = 0; reg < 4; ++reg)
            l_run[reg] = l_run[reg]*fr[reg] + psum[reg];
        #pragma unroll
        for (int dt = 0; dt < 4; ++dt) o[dt] *= fv;

        // PV: P A-frag from swizzled bf16 LDS (same-wave, lgkmcnt-ordered);
        // V B-frag (row = d, k = key) from staged Vs.
        #pragma unroll
        for (int ku = 0; ku < 2; ++ku) {
            short8 pa = *(const short8*)&Pw[c15*64 + ((ku*32 + g*8) ^ ((c15 & 7) << 3))];
            #pragma unroll
            for (int dt = 0; dt < 4; ++dt) {
                const int drow = dt*16 + c15;
                short8 vb = *(const short8*)&Vs[buf][drow*64 + (((ku*4 + g) ^ (drow & 7)) * 8)];
                o[dt] = __builtin_amdgcn_mfma_f32_16x16x32_bf16(pa, vb, o[dt], 0, 0, 0);
            }
        }

        __syncthreads();   // next buf staged+landed; cur buf free for next stage
        buf ^= 1;
    }

    // store unnormalized partials + (m,l)
    const int qbase = qt*64 + w*16;
    #pragma unroll
    for (int reg = 0; reg < 4; ++reg) {
        if (c15 == 0) {
            const int qrow = qbase + 4*g + reg;
            ml[((size_t)ksp*16 + bh)*L_ + qrow] = float2{m_run[reg], l_run[reg]};
        }
    }
    float* op = Op + ((size_t)ksp*16 + bh)*L_*DK_;
    #pragma unroll
    for (int dt = 0; dt < 4; ++dt)
        #pragma unroll
        for (int reg = 0; reg < 4; ++reg)
            op[(size_t)(qbase + 4*g + reg)*DK_ + dt*16 + c15] = o[dt][reg];
}

// ---------------------------------------------------------------------------
// Combine KSPLIT partials -> bf16 context cw [B, L, H*DK].
// ---------------------------------------------------------------------------
__global__ __launch_bounds__(256)
void combine(const float* __restrict__ Op, const float2* __restrict__ ml,
             u16* __restrict__ cw)
{
    const int t = threadIdx.x;
    const size_t row = (size_t)blockIdx.x*16 + (t >> 4);  // 0..32767 (= bh*L + l)
    const int di = (t & 15) * 4;
    const float2 a = ml[row];
    const float2 b = ml[32768 + row];
    const float M  = fmaxf(a.x, b.x);
    const float e0 = __expf(a.x - M), e1 = __expf(b.x - M);
    const float inv = 1.0f / (a.y*e0 + b.y*e1);
    float4 x = *(const float4*)&Op[row*DK_ + di];
    float4 y = *(const float4*)&Op[(32768 + row)*DK_ + di];
    const int bh = (int)(row >> 11), l = (int)(row & 2047);
    const int bb = bh >> 3, h = bh & 7;
    ushort4 o4;
    o4.x = f2bf((x.x*e0 + y.x*e1) * inv);
    o4.y = f2bf((x.y*e0 + y.y*e1) * inv);
    o4.z = f2bf((x.z*e0 + y.z*e1) * inv);
    o4.w = f2bf((x.w*e0 + y.w*e1) * inv);
    *(ushort4*)&cw[((size_t)bb*L_ + l)*DM_ + h*DK_ + di] = o4;
}

// ---------------------------------------------------------------------------
// Final projection: out = cw @ Wo^T + bo, fp32 out. 128x128 tile, 2-phase.
// ---------------------------------------------------------------------------
__global__ __launch_bounds__(256)
void gemmO(const u16* __restrict__ X, const u16* __restrict__ W,
           const float* __restrict__ bias, float* __restrict__ out)
{
    __shared__ u16 As[2][128*64];
    __shared__ u16 Bs[2][128*64];

    const int t = threadIdx.x;
    const int w = t >> 6, lw = t & 63;
    const int g = lw >> 4, c15 = lw & 15;
    const int wx = w & 1, wy = w >> 1;
    const int m0 = blockIdx.x * 128, n0 = blockIdx.y * 128;
    const int rs0 = w*8 + (lw >> 3);
    const int cs0 = lw & 7;

    f32x4 acc[4][4];
    #pragma unroll
    for (int mi = 0; mi < 4; ++mi)
        #pragma unroll
        for (int ni = 0; ni < 4; ++ni) acc[mi][ni] = f32x4{0.f,0.f,0.f,0.f};

    #pragma unroll
    for (int j = 0; j < 4; ++j) {
        const int r = rs0 + j*32;
        const int csrc = (cs0 ^ (r & 7)) * 8;
        gld16(X + (size_t)(m0 + r)*DM_ + csrc, &As[0][w*512 + j*2048]);
        gld16(W + (size_t)(n0 + r)*DM_ + csrc, &Bs[0][w*512 + j*2048]);
    }
    __syncthreads();

    int buf = 0;
    for (int k0 = 0; k0 < DM_; k0 += 64) {
        if (k0 + 64 < DM_) {
            #pragma unroll
            for (int j = 0; j < 4; ++j) {
                const int r = rs0 + j*32;
                const int csrc = (cs0 ^ (r & 7)) * 8;
                gld16(X + (size_t)(m0 + r)*DM_ + k0 + 64 + csrc, &As[buf^1][w*512 + j*2048]);
                gld16(W + (size_t)(n0 + r)*DM_ + k0 + 64 + csrc, &Bs[buf^1][w*512 + j*2048]);
            }
        }
        #pragma unroll
        for (int ks = 0; ks < 2; ++ks) {
            short8 af[4], bf[4];
            #pragma unroll
            for (int mi = 0; mi < 4; ++mi) {
                const int ar = wy*64 + mi*16 + c15;
                af[mi] = *(const short8*)&As[buf][ar*64 + (((ks*4 + g) ^ (ar & 7)) * 8)];
            }
            #pragma unroll
            for (int ni = 0; ni < 4; ++ni) {
                const int br = wx*64 + ni*16 + c15;
                bf[ni] = *(const short8*)&Bs[buf][br*64 + (((ks*4 + g) ^ (br & 7)) * 8)];
            }
            #pragma unroll
            for (int mi = 0; mi < 4; ++mi)
                #pragma unroll
                for (int ni = 0; ni < 4; ++ni)
                    acc[mi][ni] = __builtin_amdgcn_mfma_f32_16x16x32_bf16(
                        af[mi], bf[ni], acc[mi][ni], 0, 0, 0);
        }
        __syncthreads();
        buf ^= 1;
    }

    #pragma unroll
    for (int ni = 0; ni < 4; ++ni) {
        const int n = n0 + wx*64 + ni*16 + c15;
        const float bv = bias[n];
        #pragma unroll
        for (int mi = 0; mi < 4; ++mi) {
            #pragma unroll
            for (int reg = 0; reg < 4; ++reg) {
                const int m = m0 + wy*64 + mi*16 + 4*g + reg;
                out[(size_t)m * DM_ + n] = acc[mi][ni][reg] + bv;
            }
        }
    }
}

// ---------------------------------------------------------------------------
extern "C" void kernel_launch(void* const* d_in, const int* in_sizes, int n_in,
                              void* d_out, int out_size, void* d_ws, size_t ws_size,
                              hipStream_t stream)
{
    const float* Q  = (const float*)d_in[0];
    const float* K  = (const float*)d_in[1];
    const float* V  = (const float*)d_in[2];
    const float* Wq = (const float*)d_in[3];
    const float* bq = (const float*)d_in[4];
    const float* Wk = (const float*)d_in[5];
    const float* bk = (const float*)d_in[6];
    const float* Wv = (const float*)d_in[7];
    const float* bv = (const float*)d_in[8];
    const float* Wo = (const float*)d_in[9];
    const float* bo = (const float*)d_in[10];
    // d_in[11] = index_sample: provably unused (n_top == L -> top_k is a
    // permutation -> the scatter overwrites the whole mean-context baseline).

    char* w8 = (char*)d_ws;
    const size_t MB = 1u << 20;
    // bf16 conversions at offset 0: Wq,Wk,Wv,Wo (0..2MB), Q,K,V (2..14MB)
    u16* Wqb = (u16*)(w8);
    u16* Wkb = Wqb + 262144;
    u16* Wvb = Wkb + 262144;
    u16* Wob = Wvb + 262144;
    u16* Qb  = Wob + 262144;          // byte offset 2MB
    u16* Kb  = Qb + 2097152;
    u16* Vb  = Kb + 2097152;
    // Op partials (2 x 8MB f32) ALIAS Qb..Vb (dead after proj3): bytes 2..18MB
    float*  Op = (float*)(w8 + 2*MB);
    float2* ml = (float2*)(w8 + 18*MB);          // 512KB
    u16* qw  = (u16*)(w8 + 19*MB);               // [B,H,L,DK] bf16, pre-scaled
    u16* kw  = (u16*)(w8 + 23*MB);               // [B,H,L,DK] bf16
    u16* vtw = (u16*)(w8 + 27*MB);               // [B,H,DK,L] bf16
    u16* cw  = (u16*)(w8 + 19*MB);               // ALIAS qw/kw (dead after attn)

    cvt7<<<3584, 256, 0, stream>>>(Wq, Wk, Wv, Wo, Q, K, V, Wqb);

    dim3 blk(256);
    proj3<<<dim3(32, 4, 3), blk, 0, stream>>>(Qb, Kb, Vb, Wqb, Wkb, Wvb,
                                              bq, bk, bv, qw, kw, vtw);

    attn_kv<<<dim3(16, 32, KSPLIT), blk, 0, stream>>>(qw, kw, vtw, Op, ml);

    combine<<<2048, blk, 0, stream>>>(Op, ml, cw);

    gemmO<<<dim3(32, 4), blk, 0, stream>>>(cw, Wob, bo, (float*)d_out);
}

// Round 7
// 162.479 us; speedup vs baseline: 1.6685x; 1.0979x over previous
//
#include <hip/hip_runtime.h>
#include <hip/hip_bf16.h>
#include <math.h>

#define B_ 2
#define L_ 2048
#define DM_ 512
#define H_ 8
#define DK_ 64
#define SCALE_ 0.125f   // 1/sqrt(64), folded into Q projection epilogue
#define KSPLIT 2
#define KTILES (L_ / 64 / KSPLIT)   // 16 key-tiles per split

typedef __attribute__((ext_vector_type(8))) short short8;      // MFMA bf16 A/B frag
typedef __attribute__((ext_vector_type(8))) unsigned short ushort8;
typedef __attribute__((ext_vector_type(4))) float f32x4;       // MFMA C/D frag 16x16
typedef __attribute__((ext_vector_type(16))) float f32x16;     // MFMA C/D frag 32x32
typedef __attribute__((ext_vector_type(4))) unsigned u32x4;
typedef unsigned short u16;
typedef unsigned u32;

__device__ __forceinline__ u16 f2bf(float x) {
    __hip_bfloat16 h = __float2bfloat16(x);
    u16 r; __builtin_memcpy(&r, &h, 2); return r;
}

// async global->LDS, 16B/lane; LDS dest is wave-uniform base + laneInWave*16
__device__ __forceinline__ void gld16(const u16* g, u16* l) {
    __builtin_amdgcn_global_load_lds(
        (const __attribute__((address_space(1))) void*)g,
        (__attribute__((address_space(3))) void*)l, 16, 0, 0);
}

// ---------------------------------------------------------------------------
// Fused fp32->bf16 conversion. Order: Wq,Wk,Wv,Wo (256K each), Q,K,V (2M each)
// ---------------------------------------------------------------------------
__global__ __launch_bounds__(256)
void cvt7(const float* __restrict__ s0, const float* __restrict__ s1,
          const float* __restrict__ s2, const float* __restrict__ s3,
          const float* __restrict__ s4, const float* __restrict__ s5,
          const float* __restrict__ s6, u16* __restrict__ dst)
{
    const size_t NW = 262144, NB = 2097152;
    size_t i = ((size_t)blockIdx.x * 256 + threadIdx.x) * 8;
    const float* s; size_t off;
    if      (i < NW)            { s = s0; off = 0; }
    else if (i < 2*NW)          { s = s1; off = NW; }
    else if (i < 3*NW)          { s = s2; off = 2*NW; }
    else if (i < 4*NW)          { s = s3; off = 3*NW; }
    else if (i < 4*NW + NB)     { s = s4; off = 4*NW; }
    else if (i < 4*NW + 2*NB)   { s = s5; off = 4*NW + NB; }
    else                        { s = s6; off = 4*NW + 2*NB; }
    const float* p = s + (i - off);
    float4 x = *(const float4*)p;
    float4 y = *(const float4*)(p + 4);
    ushort8 o;
    o[0]=f2bf(x.x); o[1]=f2bf(x.y); o[2]=f2bf(x.z); o[3]=f2bf(x.w);
    o[4]=f2bf(y.x); o[5]=f2bf(y.y); o[6]=f2bf(y.z); o[7]=f2bf(y.w);
    *(ushort8*)&dst[i] = o;
}

// ---------------------------------------------------------------------------
// Fused Q/K/V projection GEMM, 128x128 tile, BK=64, 4 waves, 2-phase dbuf.
// (UNCHANGED from round 6 — isolating this round's change to attention.)
// ---------------------------------------------------------------------------
__global__ __launch_bounds__(256)
void proj3(const u16* __restrict__ Xq, const u16* __restrict__ Xk,
           const u16* __restrict__ Xv, const u16* __restrict__ Wqb,
           const u16* __restrict__ Wkb, const u16* __restrict__ Wvb,
           const float* __restrict__ bq, const float* __restrict__ bk,
           const float* __restrict__ bv, u16* __restrict__ qw,
           u16* __restrict__ kw, u16* __restrict__ vtw)
{
    __shared__ u16 As[2][128*64];
    __shared__ u16 Bs[2][128*64];

    const int z = blockIdx.z;
    const u16* X = (z==0) ? Xq : (z==1) ? Xk : Xv;
    const u16* W = (z==0) ? Wqb : (z==1) ? Wkb : Wvb;
    const float* bias = (z==0) ? bq : (z==1) ? bk : bv;

    const int t = threadIdx.x;
    const int w = t >> 6, lw = t & 63;
    const int g = lw >> 4, c15 = lw & 15;
    const int wx = w & 1, wy = w >> 1;
    const int m0 = blockIdx.x * 128, n0 = blockIdx.y * 128;
    const int rs0 = w*8 + (lw >> 3);
    const int cs0 = lw & 7;

    f32x4 acc[4][4];
    #pragma unroll
    for (int mi = 0; mi < 4; ++mi)
        #pragma unroll
        for (int ni = 0; ni < 4; ++ni) acc[mi][ni] = f32x4{0.f,0.f,0.f,0.f};

    #pragma unroll
    for (int j = 0; j < 4; ++j) {
        const int r = rs0 + j*32;
        const int csrc = (cs0 ^ (r & 7)) * 8;
        gld16(X + (size_t)(m0 + r)*DM_ + csrc, &As[0][w*512 + j*2048]);
        gld16(W + (size_t)(n0 + r)*DM_ + csrc, &Bs[0][w*512 + j*2048]);
    }
    __syncthreads();

    int buf = 0;
    for (int k0 = 0; k0 < DM_; k0 += 64) {
        if (k0 + 64 < DM_) {
            #pragma unroll
            for (int j = 0; j < 4; ++j) {
                const int r = rs0 + j*32;
                const int csrc = (cs0 ^ (r & 7)) * 8;
                gld16(X + (size_t)(m0 + r)*DM_ + k0 + 64 + csrc, &As[buf^1][w*512 + j*2048]);
                gld16(W + (size_t)(n0 + r)*DM_ + k0 + 64 + csrc, &Bs[buf^1][w*512 + j*2048]);
            }
        }
        #pragma unroll
        for (int ks = 0; ks < 2; ++ks) {
            short8 af[4], bf[4];
            #pragma unroll
            for (int mi = 0; mi < 4; ++mi) {
                const int ar = wy*64 + mi*16 + c15;
                af[mi] = *(const short8*)&As[buf][ar*64 + (((ks*4 + g) ^ (ar & 7)) * 8)];
            }
            #pragma unroll
            for (int ni = 0; ni < 4; ++ni) {
                const int br = wx*64 + ni*16 + c15;
                bf[ni] = *(const short8*)&Bs[buf][br*64 + (((ks*4 + g) ^ (br & 7)) * 8)];
            }
            #pragma unroll
            for (int mi = 0; mi < 4; ++mi)
                #pragma unroll
                for (int ni = 0; ni < 4; ++ni)
                    acc[mi][ni] = __builtin_amdgcn_mfma_f32_16x16x32_bf16(
                        af[mi], bf[ni], acc[mi][ni], 0, 0, 0);
        }
        __syncthreads();
        buf ^= 1;
    }

    const int bb = m0 >> 11;
    const int l0 = m0 & (L_ - 1);
    if (z < 2) {
        u16* out = (z == 0) ? qw : kw;
        const float sc = (z == 0) ? SCALE_ : 1.0f;
        #pragma unroll
        for (int ni = 0; ni < 4; ++ni) {
            const int n = n0 + wx*64 + ni*16 + c15;
            const int h = n >> 6, dk = n & 63;
            const float bv2 = bias[n];
            #pragma unroll
            for (int mi = 0; mi < 4; ++mi) {
                #pragma unroll
                for (int reg = 0; reg < 4; ++reg) {
                    const int l = l0 + wy*64 + mi*16 + 4*g + reg;
                    out[(((size_t)bb*H_ + h)*L_ + l)*DK_ + dk] =
                        f2bf((acc[mi][ni][reg] + bv2) * sc);
                }
            }
        }
    } else {
        #pragma unroll
        for (int ni = 0; ni < 4; ++ni) {
            const int n = n0 + wx*64 + ni*16 + c15;
            const int h = n >> 6, dk = n & 63;
            const float bv2 = bias[n];
            #pragma unroll
            for (int mi = 0; mi < 4; ++mi) {
                const int l = l0 + wy*64 + mi*16 + 4*g;
                ushort4 o4;
                o4.x = f2bf(acc[mi][ni][0] + bv2);
                o4.y = f2bf(acc[mi][ni][1] + bv2);
                o4.z = f2bf(acc[mi][ni][2] + bv2);
                o4.w = f2bf(acc[mi][ni][3] + bv2);
                *(ushort4*)&vtw[(((size_t)bb*H_ + h)*DK_ + dk)*L_ + l] = o4;
            }
        }
    }
}

// ---------------------------------------------------------------------------
// Flash attention v3: 32x32 MFMA, SWAPPED operands (T12 structure).
// S^T = mfma(K, Q): q = lane&31, each lane holds 32 of 64 keys (partner
// lane^32 holds the rest). Softmax fully in-register: 31 local fmax/add +
// ONE shfl_xor(32). P^T -> PV B-frag via cndmask select + shfl_xor(32).
// PV swapped too: O^T = mfma(V^T, P^T). K/V LDS staging/swizzle/dbuf and
// Op/ml output format identical to round 6. 4 waves x 32 q = 128 q/block.
// Grid (bh=16, qt=16, ks=2) = 512 blocks.
// C/D layout 32x32 (m101): col = lane&31, row = (reg&3)+8*(reg>>2)+4*(lane>>5)
// ---------------------------------------------------------------------------
__global__ __launch_bounds__(256)
void attn2(const u16* __restrict__ qg, const u16* __restrict__ kg,
           const u16* __restrict__ vtg, float* __restrict__ Op,
           float2* __restrict__ ml)
{
    __shared__ char smem[34816];            // 32KB K/V dbuf; 34KB transpose after
    u16* KsB = (u16*)smem;                  // [2][64*64]
    u16* VsB = (u16*)(smem + 16384);        // [2][64*64]

    const int t  = threadIdx.x;
    const int w  = t >> 6, lw = t & 63;
    const int lq = lw & 31;                 // q within wave's 32-row block
    const int hi = lw >> 5;
    const int bh = blockIdx.x, qt = blockIdx.y, ksp = blockIdx.z;

    const u16* kp = kg + (size_t)bh*L_*DK_;
    const u16* vp = vtg + (size_t)bh*DK_*L_;
    const int qglob = qt*128 + w*32 + lq;   // this lane's query row

    // Q B-frag: col = lane&31 = q, k = hi*8 + j within each 16-k step
    short8 qf[4];
    {
        const u16* qp = qg + ((size_t)bh*L_ + qglob) * DK_;
        #pragma unroll
        for (int st = 0; st < 4; ++st)
            qf[st] = *(const short8*)&qp[st*16 + hi*8];
    }

    f32x16 oacc[2];
    #pragma unroll
    for (int dt = 0; dt < 2; ++dt)
        #pragma unroll
        for (int r = 0; r < 16; ++r) oacc[dt][r] = 0.f;
    float m_run = -1e30f, l_run = 0.f;

    const int rs0 = w*8 + (lw >> 3);
    const int cs0 = lw & 7;

    // prologue: stage first tile into buf 0
    {
        const int kt = ksp * KTILES;
        #pragma unroll
        for (int j = 0; j < 2; ++j) {
            const int r = rs0 + j*32;
            const int csrc = (cs0 ^ (r & 7)) * 8;
            gld16(kp + (size_t)(kt*64 + r)*DK_ + csrc, KsB + j*2048 + w*512);
            gld16(vp + (size_t)r*L_ + kt*64 + csrc,    VsB + j*2048 + w*512);
        }
    }
    __syncthreads();

    int buf = 0;
    for (int tt = 0; tt < KTILES; ++tt) {
        const int kt = ksp * KTILES + tt;
        if (tt + 1 < KTILES) {
            #pragma unroll
            for (int j = 0; j < 2; ++j) {
                const int r = rs0 + j*32;
                const int csrc = (cs0 ^ (r & 7)) * 8;
                gld16(kp + (size_t)((kt+1)*64 + r)*DK_ + csrc,
                      KsB + (buf^1)*4096 + j*2048 + w*512);
                gld16(vp + (size_t)r*L_ + (kt+1)*64 + csrc,
                      VsB + (buf^1)*4096 + j*2048 + w*512);
            }
        }
        const u16* Ks = KsB + buf*4096;
        const u16* Vs = VsB + buf*4096;

        // ---- S^T = K Q^T : A = K rows(keys), B = Q cols(q). 2 key-blocks.
        f32x16 sacc[2];
        #pragma unroll
        for (int nt = 0; nt < 2; ++nt)
            #pragma unroll
            for (int r = 0; r < 16; ++r) sacc[nt][r] = 0.f;
        #pragma unroll
        for (int st = 0; st < 4; ++st) {
            #pragma unroll
            for (int nt = 0; nt < 2; ++nt) {
                const int key = nt*32 + lq;
                short8 kf = *(const short8*)&Ks[key*64 + (((2*st + hi) ^ (key & 7)) * 8)];
                sacc[nt] = __builtin_amdgcn_mfma_f32_32x32x16_bf16(
                    kf, qf[st], sacc[nt], 0, 0, 0);
            }
        }

        // ---- online softmax (per-lane scalar; q = lq, 32 keys local)
        float tmax = sacc[0][0];
        #pragma unroll
        for (int nt = 0; nt < 2; ++nt)
            #pragma unroll
            for (int r = 0; r < 16; ++r) tmax = fmaxf(tmax, sacc[nt][r]);
        tmax = fmaxf(tmax, __shfl_xor(tmax, 32, 64));
        const float mn = fmaxf(m_run, tmax);
        const float fr = __expf(m_run - mn);
        m_run = mn;
        float psum = 0.f;
        #pragma unroll
        for (int nt = 0; nt < 2; ++nt)
            #pragma unroll
            for (int r = 0; r < 16; ++r) {
                const float p = __expf(sacc[nt][r] - mn);
                sacc[nt][r] = p;
                psum += p;
            }
        psum += __shfl_xor(psum, 32, 64);
        l_run = l_run * fr + psum;
        #pragma unroll
        for (int dt = 0; dt < 2; ++dt)
            #pragma unroll
            for (int r = 0; r < 16; ++r) oacc[dt][r] *= fr;

        // ---- pack P -> bf16 pairs: pk[nt][mp][pp] = keys nt*32+8mp+4hi+{2pp,2pp+1}
        u32 pk[2][4][2];
        #pragma unroll
        for (int nt = 0; nt < 2; ++nt)
            #pragma unroll
            for (int mp = 0; mp < 4; ++mp)
                #pragma unroll
                for (int pp = 0; pp < 2; ++pp)
                    pk[nt][mp][pp] = (u32)f2bf(sacc[nt][4*mp + 2*pp])
                                   | ((u32)f2bf(sacc[nt][4*mp + 2*pp + 1]) << 16);

        // ---- PV: per ks step build B-frag P^T[key=ks*16+hi*8+j][q] then MFMA
        #pragma unroll
        for (int ks = 0; ks < 4; ++ks) {
            const int nt = ks >> 1, bsel = ks & 1;
            // lane passes the m-block its partner needs, keeps the other
            u32 pass0 = hi ? pk[nt][2*bsel][0] : pk[nt][2*bsel+1][0];
            u32 pass1 = hi ? pk[nt][2*bsel][1] : pk[nt][2*bsel+1][1];
            u32 r0 = __shfl_xor(pass0, 32, 64);
            u32 r1 = __shfl_xor(pass1, 32, 64);
            u32x4 pw;
            pw[0] = hi ? r0 : pk[nt][2*bsel][0];     // j 0,1
            pw[1] = hi ? r1 : pk[nt][2*bsel][1];     // j 2,3
            pw[2] = hi ? pk[nt][2*bsel+1][0] : r0;   // j 4,5
            pw[3] = hi ? pk[nt][2*bsel+1][1] : r1;   // j 6,7
            short8 pb = __builtin_bit_cast(short8, pw);
            #pragma unroll
            for (int dt = 0; dt < 2; ++dt) {
                const int d = dt*32 + lq;
                short8 vf = *(const short8*)&Vs[d*64 + (((2*ks + hi) ^ (d & 7)) * 8)];
                oacc[dt] = __builtin_amdgcn_mfma_f32_32x32x16_bf16(
                    vf, pb, oacc[dt], 0, 0, 0);
            }
        }

        __syncthreads();
        buf ^= 1;
    }

    // ---- epilogue: O^T[d][q] -> Op[q][d] via LDS transpose (stride 68 pad)
    __syncthreads();   // all waves done with K/V LDS
    float* tw = (float*)smem + w * 2176;   // 32 rows x 68 floats per wave
    #pragma unroll
    for (int dt = 0; dt < 2; ++dt)
        #pragma unroll
        for (int r = 0; r < 16; ++r) {
            const int d = dt*32 + (r & 3) + 8*(r >> 2) + 4*hi;
            tw[lq*68 + d] = oacc[dt][r];
        }
    // same-wave write->read, DS pipe in-order per wave (lgkmcnt ordered)
    float* op = Op + ((size_t)ksp*16 + bh)*L_*DK_ + (size_t)qglob*DK_;
    #pragma unroll
    for (int p4 = 0; p4 < 8; ++p4) {
        const int d0 = hi*32 + p4*4;
        float4 v = *(const float4*)&tw[lq*68 + d0];
        *(float4*)&op[d0] = v;
    }
    if (hi == 0)
        ml[((size_t)ksp*16 + bh)*L_ + qglob] = float2{m_run, l_run};
}

// ---------------------------------------------------------------------------
// Combine KSPLIT partials -> bf16 context cw [B, L, H*DK]. (unchanged)
// ---------------------------------------------------------------------------
__global__ __launch_bounds__(256)
void combine(const float* __restrict__ Op, const float2* __restrict__ ml,
             u16* __restrict__ cw)
{
    const int t = threadIdx.x;
    const size_t row = (size_t)blockIdx.x*16 + (t >> 4);
    const int di = (t & 15) * 4;
    const float2 a = ml[row];
    const float2 b = ml[32768 + row];
    const float M  = fmaxf(a.x, b.x);
    const float e0 = __expf(a.x - M), e1 = __expf(b.x - M);
    const float inv = 1.0f / (a.y*e0 + b.y*e1);
    float4 x = *(const float4*)&Op[row*DK_ + di];
    float4 y = *(const float4*)&Op[(32768 + row)*DK_ + di];
    const int bh = (int)(row >> 11), l = (int)(row & 2047);
    const int bb = bh >> 3, h = bh & 7;
    ushort4 o4;
    o4.x = f2bf((x.x*e0 + y.x*e1) * inv);
    o4.y = f2bf((x.y*e0 + y.y*e1) * inv);
    o4.z = f2bf((x.z*e0 + y.z*e1) * inv);
    o4.w = f2bf((x.w*e0 + y.w*e1) * inv);
    *(ushort4*)&cw[((size_t)bb*L_ + l)*DM_ + h*DK_ + di] = o4;
}

// ---------------------------------------------------------------------------
// Final projection: out = cw @ Wo^T + bo, fp32 out. 128x128, 2-phase dbuf.
// (UNCHANGED from round 6.)
// ---------------------------------------------------------------------------
__global__ __launch_bounds__(256)
void gemmO(const u16* __restrict__ X, const u16* __restrict__ W,
           const float* __restrict__ bias, float* __restrict__ out)
{
    __shared__ u16 As[2][128*64];
    __shared__ u16 Bs[2][128*64];

    const int t = threadIdx.x;
    const int w = t >> 6, lw = t & 63;
    const int g = lw >> 4, c15 = lw & 15;
    const int wx = w & 1, wy = w >> 1;
    const int m0 = blockIdx.x * 128, n0 = blockIdx.y * 128;
    const int rs0 = w*8 + (lw >> 3);
    const int cs0 = lw & 7;

    f32x4 acc[4][4];
    #pragma unroll
    for (int mi = 0; mi < 4; ++mi)
        #pragma unroll
        for (int ni = 0; ni < 4; ++ni) acc[mi][ni] = f32x4{0.f,0.f,0.f,0.f};

    #pragma unroll
    for (int j = 0; j < 4; ++j) {
        const int r = rs0 + j*32;
        const int csrc = (cs0 ^ (r & 7)) * 8;
        gld16(X + (size_t)(m0 + r)*DM_ + csrc, &As[0][w*512 + j*2048]);
        gld16(W + (size_t)(n0 + r)*DM_ + csrc, &Bs[0][w*512 + j*2048]);
    }
    __syncthreads();

    int buf = 0;
    for (int k0 = 0; k0 < DM_; k0 += 64) {
        if (k0 + 64 < DM_) {
            #pragma unroll
            for (int j = 0; j < 4; ++j) {
                const int r = rs0 + j*32;
                const int csrc = (cs0 ^ (r & 7)) * 8;
                gld16(X + (size_t)(m0 + r)*DM_ + k0 + 64 + csrc, &As[buf^1][w*512 + j*2048]);
                gld16(W + (size_t)(n0 + r)*DM_ + k0 + 64 + csrc, &Bs[buf^1][w*512 + j*2048]);
            }
        }
        #pragma unroll
        for (int ks = 0; ks < 2; ++ks) {
            short8 af[4], bf[4];
            #pragma unroll
            for (int mi = 0; mi < 4; ++mi) {
                const int ar = wy*64 + mi*16 + c15;
                af[mi] = *(const short8*)&As[buf][ar*64 + (((ks*4 + g) ^ (ar & 7)) * 8)];
            }
            #pragma unroll
            for (int ni = 0; ni < 4; ++ni) {
                const int br = wx*64 + ni*16 + c15;
                bf[ni] = *(const short8*)&Bs[buf][br*64 + (((ks*4 + g) ^ (br & 7)) * 8)];
            }
            #pragma unroll
            for (int mi = 0; mi < 4; ++mi)
                #pragma unroll
                for (int ni = 0; ni < 4; ++ni)
                    acc[mi][ni] = __builtin_amdgcn_mfma_f32_16x16x32_bf16(
                        af[mi], bf[ni], acc[mi][ni], 0, 0, 0);
        }
        __syncthreads();
        buf ^= 1;
    }

    #pragma unroll
    for (int ni = 0; ni < 4; ++ni) {
        const int n = n0 + wx*64 + ni*16 + c15;
        const float bv = bias[n];
        #pragma unroll
        for (int mi = 0; mi < 4; ++mi) {
            #pragma unroll
            for (int reg = 0; reg < 4; ++reg) {
                const int m = m0 + wy*64 + mi*16 + 4*g + reg;
                out[(size_t)m * DM_ + n] = acc[mi][ni][reg] + bv;
            }
        }
    }
}

// ---------------------------------------------------------------------------
extern "C" void kernel_launch(void* const* d_in, const int* in_sizes, int n_in,
                              void* d_out, int out_size, void* d_ws, size_t ws_size,
                              hipStream_t stream)
{
    const float* Q  = (const float*)d_in[0];
    const float* K  = (const float*)d_in[1];
    const float* V  = (const float*)d_in[2];
    const float* Wq = (const float*)d_in[3];
    const float* bq = (const float*)d_in[4];
    const float* Wk = (const float*)d_in[5];
    const float* bk = (const float*)d_in[6];
    const float* Wv = (const float*)d_in[7];
    const float* bv = (const float*)d_in[8];
    const float* Wo = (const float*)d_in[9];
    const float* bo = (const float*)d_in[10];
    // d_in[11] = index_sample: provably unused (n_top == L -> top_k is a
    // permutation -> the scatter overwrites the whole mean-context baseline).

    char* w8 = (char*)d_ws;
    const size_t MB = 1u << 20;
    u16* Wqb = (u16*)(w8);
    u16* Wkb = Wqb + 262144;
    u16* Wvb = Wkb + 262144;
    u16* Wob = Wvb + 262144;
    u16* Qb  = Wob + 262144;          // byte offset 2MB
    u16* Kb  = Qb + 2097152;
    u16* Vb  = Kb + 2097152;
    float*  Op = (float*)(w8 + 2*MB);            // alias Qb..Vb (dead after proj3)
    float2* ml = (float2*)(w8 + 18*MB);
    u16* qw  = (u16*)(w8 + 19*MB);
    u16* kw  = (u16*)(w8 + 23*MB);
    u16* vtw = (u16*)(w8 + 27*MB);
    u16* cw  = (u16*)(w8 + 19*MB);               // alias qw/kw (dead after attn)

    cvt7<<<3584, 256, 0, stream>>>(Wq, Wk, Wv, Wo, Q, K, V, Wqb);

    dim3 blk(256);
    proj3<<<dim3(32, 4, 3), blk, 0, stream>>>(Qb, Kb, Vb, Wqb, Wkb, Wvb,
                                              bq, bk, bv, qw, kw, vtw);

    attn2<<<dim3(16, 16, KSPLIT), blk, 0, stream>>>(qw, kw, vtw, Op, ml);

    combine<<<2048, blk, 0, stream>>>(Op, ml, cw);

    gemmO<<<dim3(32, 4), blk, 0, stream>>>(cw, Wob, bo, (float*)d_out);
}

// Round 8
// 159.131 us; speedup vs baseline: 1.7036x; 1.0210x over previous
//
#include <hip/hip_runtime.h>
#include <hip/hip_bf16.h>
#include <hip/hip_fp16.h>
#include <math.h>

#define B_ 2
#define L_ 2048
#define DM_ 512
#define H_ 8
#define DK_ 64
// exp2-domain: fold log2(e) into the Q scale so softmax uses exp2 directly
#define SCALE2_ (0.125f * 1.44269504088896f)
#define KSPLIT 4
#define KTILES (L_ / 64 / KSPLIT)   // 8 key-tiles per split
#define THR_ 11.5f                  // defer-max threshold (log2 units ~ 8 nats)

typedef __attribute__((ext_vector_type(8))) short short8;      // MFMA bf16 A/B frag
typedef __attribute__((ext_vector_type(8))) unsigned short ushort8;
typedef __attribute__((ext_vector_type(4))) float f32x4;       // MFMA C/D frag 16x16
typedef __attribute__((ext_vector_type(16))) float f32x16;     // MFMA C/D frag 32x32
typedef __attribute__((ext_vector_type(4))) unsigned u32x4;
typedef unsigned short u16;
typedef unsigned u32;

__device__ __forceinline__ u16 f2bf(float x) {
    __hip_bfloat16 h = __float2bfloat16(x);
    u16 r; __builtin_memcpy(&r, &h, 2); return r;
}
__device__ __forceinline__ u16 f2h(float x) {
    __half h = __float2half(x);
    u16 r; __builtin_memcpy(&r, &h, 2); return r;
}
__device__ __forceinline__ float h2f(u16 v) {
    __half h; __builtin_memcpy(&h, &v, 2); return __half2float(h);
}
__device__ __forceinline__ short8 pack8(float4 a, float4 b) {
    ushort8 o;
    o[0]=f2bf(a.x); o[1]=f2bf(a.y); o[2]=f2bf(a.z); o[3]=f2bf(a.w);
    o[4]=f2bf(b.x); o[5]=f2bf(b.y); o[6]=f2bf(b.z); o[7]=f2bf(b.w);
    return __builtin_bit_cast(short8, o);
}

// async global->LDS, 16B/lane; LDS dest is wave-uniform base + laneInWave*16
__device__ __forceinline__ void gld16(const u16* g, u16* l) {
    __builtin_amdgcn_global_load_lds(
        (const __attribute__((address_space(1))) void*)g,
        (__attribute__((address_space(3))) void*)l, 16, 0, 0);
}

// ---------------------------------------------------------------------------
// Fused Q/K/V projection GEMM with INLINE fp32->bf16 conversion (cvt7 fused).
// 128x128 tile, BK=64, 4 waves, 2-phase dbuf. Reg-staged: load fp32 early,
// cvt+ds_write after compute (T14 split), one barrier per K-step.
// z=0: qw [B,H,L,DK] bf16 *SCALE2_.  z=1: kw *1.  z=2: vtw [B,H,DK,L].
// ---------------------------------------------------------------------------
__global__ __launch_bounds__(256)
void proj3(const float* __restrict__ Xq, const float* __restrict__ Xk,
           const float* __restrict__ Xv, const float* __restrict__ Wq,
           const float* __restrict__ Wk, const float* __restrict__ Wv,
           const float* __restrict__ bq, const float* __restrict__ bk,
           const float* __restrict__ bv, u16* __restrict__ qw,
           u16* __restrict__ kw, u16* __restrict__ vtw)
{
    __shared__ u16 As[2][128*64];
    __shared__ u16 Bs[2][128*64];

    const int z = blockIdx.z;
    const float* X = (z==0) ? Xq : (z==1) ? Xk : Xv;
    const float* W = (z==0) ? Wq : (z==1) ? Wk : Wv;
    const float* bias = (z==0) ? bq : (z==1) ? bk : bv;

    const int t = threadIdx.x;
    const int w = t >> 6, lw = t & 63;
    const int g = lw >> 4, c15 = lw & 15;
    const int wx = w & 1, wy = w >> 1;
    const int m0 = blockIdx.x * 128, n0 = blockIdx.y * 128;
    const int rs0 = w*8 + (lw >> 3);
    const int cs0 = lw & 7;

    f32x4 acc[4][4];
    #pragma unroll
    for (int mi = 0; mi < 4; ++mi)
        #pragma unroll
        for (int ni = 0; ni < 4; ++ni) acc[mi][ni] = f32x4{0.f,0.f,0.f,0.f};

    float4 xa[4][2], wa[4][2];

    // prologue: load + cvt + write k0=0 into buf 0
    #pragma unroll
    for (int j = 0; j < 4; ++j) {
        const int r = rs0 + j*32;
        const int c8 = (cs0 ^ (r & 7)) * 8;
        xa[j][0] = *(const float4*)&X[(size_t)(m0 + r)*DM_ + c8];
        xa[j][1] = *(const float4*)&X[(size_t)(m0 + r)*DM_ + c8 + 4];
        wa[j][0] = *(const float4*)&W[(size_t)(n0 + r)*DM_ + c8];
        wa[j][1] = *(const float4*)&W[(size_t)(n0 + r)*DM_ + c8 + 4];
    }
    #pragma unroll
    for (int j = 0; j < 4; ++j) {
        *(short8*)&As[0][w*512 + j*2048 + lw*8] = pack8(xa[j][0], xa[j][1]);
        *(short8*)&Bs[0][w*512 + j*2048 + lw*8] = pack8(wa[j][0], wa[j][1]);
    }
    __syncthreads();

    int buf = 0;
    for (int k0 = 0; k0 < DM_; k0 += 64) {
        const bool nxt = (k0 + 64 < DM_);
        if (nxt) {
            #pragma unroll
            for (int j = 0; j < 4; ++j) {
                const int r = rs0 + j*32;
                const int c8 = (cs0 ^ (r & 7)) * 8;
                xa[j][0] = *(const float4*)&X[(size_t)(m0 + r)*DM_ + k0 + 64 + c8];
                xa[j][1] = *(const float4*)&X[(size_t)(m0 + r)*DM_ + k0 + 64 + c8 + 4];
                wa[j][0] = *(const float4*)&W[(size_t)(n0 + r)*DM_ + k0 + 64 + c8];
                wa[j][1] = *(const float4*)&W[(size_t)(n0 + r)*DM_ + k0 + 64 + c8 + 4];
            }
        }
        #pragma unroll
        for (int ks = 0; ks < 2; ++ks) {
            short8 af[4], bf[4];
            #pragma unroll
            for (int mi = 0; mi < 4; ++mi) {
                const int ar = wy*64 + mi*16 + c15;
                af[mi] = *(const short8*)&As[buf][ar*64 + (((ks*4 + g) ^ (ar & 7)) * 8)];
            }
            #pragma unroll
            for (int ni = 0; ni < 4; ++ni) {
                const int br = wx*64 + ni*16 + c15;
                bf[ni] = *(const short8*)&Bs[buf][br*64 + (((ks*4 + g) ^ (br & 7)) * 8)];
            }
            #pragma unroll
            for (int mi = 0; mi < 4; ++mi)
                #pragma unroll
                for (int ni = 0; ni < 4; ++ni)
                    acc[mi][ni] = __builtin_amdgcn_mfma_f32_16x16x32_bf16(
                        af[mi], bf[ni], acc[mi][ni], 0, 0, 0);
        }
        if (nxt) {
            #pragma unroll
            for (int j = 0; j < 4; ++j) {
                *(short8*)&As[buf^1][w*512 + j*2048 + lw*8] = pack8(xa[j][0], xa[j][1]);
                *(short8*)&Bs[buf^1][w*512 + j*2048 + lw*8] = pack8(wa[j][0], wa[j][1]);
            }
        }
        __syncthreads();
        buf ^= 1;
    }

    // C/D: row = 4*(lane>>4)+reg, col = lane&15
    const int bb = m0 >> 11;
    const int l0 = m0 & (L_ - 1);
    if (z < 2) {
        u16* out = (z == 0) ? qw : kw;
        const float sc = (z == 0) ? SCALE2_ : 1.0f;
        #pragma unroll
        for (int ni = 0; ni < 4; ++ni) {
            const int n = n0 + wx*64 + ni*16 + c15;
            const int h = n >> 6, dk = n & 63;
            const float bv2 = bias[n];
            #pragma unroll
            for (int mi = 0; mi < 4; ++mi) {
                #pragma unroll
                for (int reg = 0; reg < 4; ++reg) {
                    const int l = l0 + wy*64 + mi*16 + 4*g + reg;
                    out[(((size_t)bb*H_ + h)*L_ + l)*DK_ + dk] =
                        f2bf((acc[mi][ni][reg] + bv2) * sc);
                }
            }
        }
    } else {
        #pragma unroll
        for (int ni = 0; ni < 4; ++ni) {
            const int n = n0 + wx*64 + ni*16 + c15;
            const int h = n >> 6, dk = n & 63;
            const float bv2 = bias[n];
            #pragma unroll
            for (int mi = 0; mi < 4; ++mi) {
                const int l = l0 + wy*64 + mi*16 + 4*g;
                ushort4 o4;
                o4.x = f2bf(acc[mi][ni][0] + bv2);
                o4.y = f2bf(acc[mi][ni][1] + bv2);
                o4.z = f2bf(acc[mi][ni][2] + bv2);
                o4.w = f2bf(acc[mi][ni][3] + bv2);
                *(ushort4*)&vtw[(((size_t)bb*H_ + h)*DK_ + dk)*L_ + l] = o4;
            }
        }
    }
}

// ---------------------------------------------------------------------------
// Flash attention v4: 32x32 swapped MFMA; KSPLIT=4; exp2-domain softmax with
// defer-max; per-lane l_run; normalized f16 partial store.
// Grid (bh=16, qt=16, ks=4) = 1024 blocks, 4 waves -> 16 waves/CU.
// Oph[(ksp*16+bh)*L + q][64] f16 = O/l;  ml[(ksp*16+bh)*L + q] = (m, l).
// ---------------------------------------------------------------------------
__global__ __launch_bounds__(256, 4)
void attn2(const u16* __restrict__ qg, const u16* __restrict__ kg,
           const u16* __restrict__ vtg, u16* __restrict__ Oph,
           float2* __restrict__ ml)
{
    __shared__ char smem[34816];            // 32KB K/V dbuf; 34KB transpose after
    u16* KsB = (u16*)smem;                  // [2][64*64]
    u16* VsB = (u16*)(smem + 16384);        // [2][64*64]

    const int t  = threadIdx.x;
    const int w  = t >> 6, lw = t & 63;
    const int lq = lw & 31;
    const int hi = lw >> 5;
    const int bh = blockIdx.x, qt = blockIdx.y, ksp = blockIdx.z;

    const u16* kp = kg + (size_t)bh*L_*DK_;
    const u16* vp = vtg + (size_t)bh*DK_*L_;
    const int qglob = qt*128 + w*32 + lq;

    short8 qf[4];
    {
        const u16* qp = qg + ((size_t)bh*L_ + qglob) * DK_;
        #pragma unroll
        for (int st = 0; st < 4; ++st)
            qf[st] = *(const short8*)&qp[st*16 + hi*8];
    }

    f32x16 oacc[2];
    #pragma unroll
    for (int dt = 0; dt < 2; ++dt)
        #pragma unroll
        for (int r = 0; r < 16; ++r) oacc[dt][r] = 0.f;
    float m_run = -1e30f, l_run = 0.f;

    const int rs0 = w*8 + (lw >> 3);
    const int cs0 = lw & 7;

    // prologue: stage first tile into buf 0
    {
        const int kt = ksp * KTILES;
        #pragma unroll
        for (int j = 0; j < 2; ++j) {
            const int r = rs0 + j*32;
            const int csrc = (cs0 ^ (r & 7)) * 8;
            gld16(kp + (size_t)(kt*64 + r)*DK_ + csrc, KsB + j*2048 + w*512);
            gld16(vp + (size_t)r*L_ + kt*64 + csrc,    VsB + j*2048 + w*512);
        }
    }
    __syncthreads();

    int buf = 0;
    for (int tt = 0; tt < KTILES; ++tt) {
        const int kt = ksp * KTILES + tt;
        if (tt + 1 < KTILES) {
            #pragma unroll
            for (int j = 0; j < 2; ++j) {
                const int r = rs0 + j*32;
                const int csrc = (cs0 ^ (r & 7)) * 8;
                gld16(kp + (size_t)((kt+1)*64 + r)*DK_ + csrc,
                      KsB + (buf^1)*4096 + j*2048 + w*512);
                gld16(vp + (size_t)r*L_ + (kt+1)*64 + csrc,
                      VsB + (buf^1)*4096 + j*2048 + w*512);
            }
        }
        const u16* Ks = KsB + buf*4096;
        const u16* Vs = VsB + buf*4096;

        // ---- S^T = K Q^T (q = lane&31; 32 keys per lane, partner has rest)
        f32x16 sacc[2];
        #pragma unroll
        for (int nt = 0; nt < 2; ++nt)
            #pragma unroll
            for (int r = 0; r < 16; ++r) sacc[nt][r] = 0.f;
        #pragma unroll
        for (int st = 0; st < 4; ++st) {
            #pragma unroll
            for (int nt = 0; nt < 2; ++nt) {
                const int key = nt*32 + lq;
                short8 kf = *(const short8*)&Ks[key*64 + (((2*st + hi) ^ (key & 7)) * 8)];
                sacc[nt] = __builtin_amdgcn_mfma_f32_32x32x16_bf16(
                    kf, qf[st], sacc[nt], 0, 0, 0);
            }
        }

        // ---- exp2-domain online softmax with defer-max
        float tmax = sacc[0][0];
        #pragma unroll
        for (int nt = 0; nt < 2; ++nt)
            #pragma unroll
            for (int r = 0; r < 16; ++r) tmax = fmaxf(tmax, sacc[nt][r]);
        tmax = fmaxf(tmax, __shfl_xor(tmax, 32, 64));
        if (!__all(tmax - m_run <= THR_)) {
            const float mn = fmaxf(m_run, tmax);
            const float fr = exp2f(m_run - mn);
            m_run = mn;
            l_run *= fr;
            #pragma unroll
            for (int dt = 0; dt < 2; ++dt)
                oacc[dt] = oacc[dt] * fr;
        }
        float psum = 0.f;
        #pragma unroll
        for (int nt = 0; nt < 2; ++nt)
            #pragma unroll
            for (int r = 0; r < 16; ++r) {
                const float p = exp2f(sacc[nt][r] - m_run);
                sacc[nt][r] = p;
                psum += p;
            }
        l_run += psum;   // per-lane; pair-summed in epilogue

        // ---- pack P -> bf16 pairs
        u32 pk[2][4][2];
        #pragma unroll
        for (int nt = 0; nt < 2; ++nt)
            #pragma unroll
            for (int mp = 0; mp < 4; ++mp)
                #pragma unroll
                for (int pp = 0; pp < 2; ++pp)
                    pk[nt][mp][pp] = (u32)f2bf(sacc[nt][4*mp + 2*pp])
                                   | ((u32)f2bf(sacc[nt][4*mp + 2*pp + 1]) << 16);

        // ---- PV: O^T = mfma(V^T, P^T) with lane-32 exchange (validated r6/r7)
        #pragma unroll
        for (int ks = 0; ks < 4; ++ks) {
            const int nt = ks >> 1, bsel = ks & 1;
            u32 pass0 = hi ? pk[nt][2*bsel][0] : pk[nt][2*bsel+1][0];
            u32 pass1 = hi ? pk[nt][2*bsel][1] : pk[nt][2*bsel+1][1];
            u32 r0 = __shfl_xor(pass0, 32, 64);
            u32 r1 = __shfl_xor(pass1, 32, 64);
            u32x4 pw;
            pw[0] = hi ? r0 : pk[nt][2*bsel][0];
            pw[1] = hi ? r1 : pk[nt][2*bsel][1];
            pw[2] = hi ? pk[nt][2*bsel+1][0] : r0;
            pw[3] = hi ? pk[nt][2*bsel+1][1] : r1;
            short8 pb = __builtin_bit_cast(short8, pw);
            #pragma unroll
            for (int dt = 0; dt < 2; ++dt) {
                const int d = dt*32 + lq;
                short8 vf = *(const short8*)&Vs[d*64 + (((2*ks + hi) ^ (d & 7)) * 8)];
                oacc[dt] = __builtin_amdgcn_mfma_f32_32x32x16_bf16(
                    vf, pb, oacc[dt], 0, 0, 0);
            }
        }

        __syncthreads();
        buf ^= 1;
    }

    // ---- epilogue: normalize, transpose O^T[d][q] -> [q][d], store f16
    const float l_tot = l_run + __shfl_xor(l_run, 32, 64);
    const float inv = 1.0f / l_tot;
    __syncthreads();   // all waves done with K/V LDS
    float* tw = (float*)smem + w * 2176;   // 32 rows x 68 floats per wave
    #pragma unroll
    for (int dt = 0; dt < 2; ++dt)
        #pragma unroll
        for (int r = 0; r < 16; ++r) {
            const int d = dt*32 + (r & 3) + 8*(r >> 2) + 4*hi;
            tw[lq*68 + d] = oacc[dt][r] * inv;
        }
    u16* op = Oph + ((size_t)(ksp*16 + bh)*L_ + qglob)*DK_;
    #pragma unroll
    for (int p4 = 0; p4 < 8; ++p4) {
        const int d0 = hi*32 + p4*4;
        float4 v = *(const float4*)&tw[lq*68 + d0];
        ushort4 o4;
        o4.x = f2h(v.x); o4.y = f2h(v.y); o4.z = f2h(v.z); o4.w = f2h(v.w);
        *(ushort4*)&op[d0] = o4;
    }
    if (hi == 0)
        ml[((size_t)ksp*16 + bh)*L_ + qglob] = float2{m_run, l_tot};
}

// ---------------------------------------------------------------------------
// Combine 4 normalized f16 splits -> bf16 context cw [B, L, H*DK].
// weight_s = l_s * 2^(m_s - M); ctx = sum w_s * c_s / sum w_s.
// ---------------------------------------------------------------------------
__global__ __launch_bounds__(256)
void combine(const u16* __restrict__ Oph, const float2* __restrict__ ml,
             u16* __restrict__ cw)
{
    const int t = threadIdx.x;
    const size_t row = (size_t)blockIdx.x*16 + (t >> 4);  // bh*L + l, 0..32767
    const int di = (t & 15) * 4;

    float2 a[KSPLIT];
    #pragma unroll
    for (int s = 0; s < KSPLIT; ++s) a[s] = ml[row + (size_t)s*32768];
    float M = a[0].x;
    #pragma unroll
    for (int s = 1; s < KSPLIT; ++s) M = fmaxf(M, a[s].x);
    float ws[KSPLIT], den = 0.f;
    #pragma unroll
    for (int s = 0; s < KSPLIT; ++s) { ws[s] = a[s].y * exp2f(a[s].x - M); den += ws[s]; }
    const float inv = 1.0f / den;

    float acc0 = 0.f, acc1 = 0.f, acc2 = 0.f, acc3 = 0.f;
    #pragma unroll
    for (int s = 0; s < KSPLIT; ++s) {
        ushort4 v = *(const ushort4*)&Oph[(row + (size_t)s*32768)*DK_ + di];
        acc0 += ws[s] * h2f(v.x);
        acc1 += ws[s] * h2f(v.y);
        acc2 += ws[s] * h2f(v.z);
        acc3 += ws[s] * h2f(v.w);
    }
    const int bh = (int)(row >> 11), l = (int)(row & 2047);
    const int bb = bh >> 3, h = bh & 7;
    ushort4 o4;
    o4.x = f2bf(acc0 * inv);
    o4.y = f2bf(acc1 * inv);
    o4.z = f2bf(acc2 * inv);
    o4.w = f2bf(acc3 * inv);
    *(ushort4*)&cw[((size_t)bb*L_ + l)*DM_ + h*DK_ + di] = o4;
}

// ---------------------------------------------------------------------------
// Final projection: out = cw @ Wo^T + bo, fp32 out. 128x128, 2-phase dbuf.
// A = cw bf16 via gld16; B = Wo fp32 reg-staged with inline cvt.
// ---------------------------------------------------------------------------
__global__ __launch_bounds__(256)
void gemmO(const u16* __restrict__ X, const float* __restrict__ W,
           const float* __restrict__ bias, float* __restrict__ out)
{
    __shared__ u16 As[2][128*64];
    __shared__ u16 Bs[2][128*64];

    const int t = threadIdx.x;
    const int w = t >> 6, lw = t & 63;
    const int g = lw >> 4, c15 = lw & 15;
    const int wx = w & 1, wy = w >> 1;
    const int m0 = blockIdx.x * 128, n0 = blockIdx.y * 128;
    const int rs0 = w*8 + (lw >> 3);
    const int cs0 = lw & 7;

    f32x4 acc[4][4];
    #pragma unroll
    for (int mi = 0; mi < 4; ++mi)
        #pragma unroll
        for (int ni = 0; ni < 4; ++ni) acc[mi][ni] = f32x4{0.f,0.f,0.f,0.f};

    float4 wa[4][2];
    #pragma unroll
    for (int j = 0; j < 4; ++j) {
        const int r = rs0 + j*32;
        const int c8 = (cs0 ^ (r & 7)) * 8;
        gld16(X + (size_t)(m0 + r)*DM_ + c8, &As[0][w*512 + j*2048]);
        wa[j][0] = *(const float4*)&W[(size_t)(n0 + r)*DM_ + c8];
        wa[j][1] = *(const float4*)&W[(size_t)(n0 + r)*DM_ + c8 + 4];
    }
    #pragma unroll
    for (int j = 0; j < 4; ++j)
        *(short8*)&Bs[0][w*512 + j*2048 + lw*8] = pack8(wa[j][0], wa[j][1]);
    __syncthreads();

    int buf = 0;
    for (int k0 = 0; k0 < DM_; k0 += 64) {
        const bool nxt = (k0 + 64 < DM_);
        if (nxt) {
            #pragma unroll
            for (int j = 0; j < 4; ++j) {
                const int r = rs0 + j*32;
                const int c8 = (cs0 ^ (r & 7)) * 8;
                gld16(X + (size_t)(m0 + r)*DM_ + k0 + 64 + c8, &As[buf^1][w*512 + j*2048]);
                wa[j][0] = *(const float4*)&W[(size_t)(n0 + r)*DM_ + k0 + 64 + c8];
                wa[j][1] = *(const float4*)&W[(size_t)(n0 + r)*DM_ + k0 + 64 + c8 + 4];
            }
        }
        #pragma unroll
        for (int ks = 0; ks < 2; ++ks) {
            short8 af[4], bf[4];
            #pragma unroll
            for (int mi = 0; mi < 4; ++mi) {
                const int ar = wy*64 + mi*16 + c15;
                af[mi] = *(const short8*)&As[buf][ar*64 + (((ks*4 + g) ^ (ar & 7)) * 8)];
            }
            #pragma unroll
            for (int ni = 0; ni < 4; ++ni) {
                const int br = wx*64 + ni*16 + c15;
                bf[ni] = *(const short8*)&Bs[buf][br*64 + (((ks*4 + g) ^ (br & 7)) * 8)];
            }
            #pragma unroll
            for (int mi = 0; mi < 4; ++mi)
                #pragma unroll
                for (int ni = 0; ni < 4; ++ni)
                    acc[mi][ni] = __builtin_amdgcn_mfma_f32_16x16x32_bf16(
                        af[mi], bf[ni], acc[mi][ni], 0, 0, 0);
        }
        if (nxt) {
            #pragma unroll
            for (int j = 0; j < 4; ++j)
                *(short8*)&Bs[buf^1][w*512 + j*2048 + lw*8] = pack8(wa[j][0], wa[j][1]);
        }
        __syncthreads();
        buf ^= 1;
    }

    #pragma unroll
    for (int ni = 0; ni < 4; ++ni) {
        const int n = n0 + wx*64 + ni*16 + c15;
        const float bv = bias[n];
        #pragma unroll
        for (int mi = 0; mi < 4; ++mi) {
            #pragma unroll
            for (int reg = 0; reg < 4; ++reg) {
                const int m = m0 + wy*64 + mi*16 + 4*g + reg;
                out[(size_t)m * DM_ + n] = acc[mi][ni][reg] + bv;
            }
        }
    }
}

// ---------------------------------------------------------------------------
extern "C" void kernel_launch(void* const* d_in, const int* in_sizes, int n_in,
                              void* d_out, int out_size, void* d_ws, size_t ws_size,
                              hipStream_t stream)
{
    const float* Q  = (const float*)d_in[0];
    const float* K  = (const float*)d_in[1];
    const float* V  = (const float*)d_in[2];
    const float* Wq = (const float*)d_in[3];
    const float* bq = (const float*)d_in[4];
    const float* Wk = (const float*)d_in[5];
    const float* bk = (const float*)d_in[6];
    const float* Wv = (const float*)d_in[7];
    const float* bv = (const float*)d_in[8];
    const float* Wo = (const float*)d_in[9];
    const float* bo = (const float*)d_in[10];
    // d_in[11] = index_sample: provably unused (n_top == L -> top_k is a
    // permutation -> the scatter overwrites the whole mean-context baseline).

    char* w8 = (char*)d_ws;
    const size_t MB = 1u << 20;
    u16*    Oph = (u16*)(w8);                    // f16 [4][16][2048][64] = 16MB
    float2* ml  = (float2*)(w8 + 16*MB);         // 1MB
    u16*    qw  = (u16*)(w8 + 17*MB);            // [B,H,L,DK] bf16, *SCALE2_
    u16*    kw  = (u16*)(w8 + 21*MB);
    u16*    vtw = (u16*)(w8 + 25*MB);            // [B,H,DK,L] bf16 (ends 29MB)
    u16*    cw  = (u16*)(w8 + 17*MB);            // ALIAS qw (dead after attn)

    dim3 blk(256);
    proj3<<<dim3(32, 4, 3), blk, 0, stream>>>(Q, K, V, Wq, Wk, Wv,
                                              bq, bk, bv, qw, kw, vtw);

    attn2<<<dim3(16, 16, KSPLIT), blk, 0, stream>>>(qw, kw, vtw, Oph, ml);

    combine<<<2048, blk, 0, stream>>>(Oph, ml, cw);

    gemmO<<<dim3(32, 4), blk, 0, stream>>>(cw, Wo, bo, (float*)d_out);
}